// Round 4
// baseline (299.826 us; speedup 1.0000x reference)
//
#include <hip/hip_runtime.h>

#define HH 1024
#define INW 512
#define BB 32
#define BG 4             // batches per block: B=32 split across 8 blocks per row
#define Z_MIN_C 0.001f
#define Z_RANGE_C 0.099f
#define E_H_C 0.5f

typedef float v4f __attribute__((ext_vector_type(4)));

__device__ __forceinline__ float sigmoidf_(float v) {
    return 1.0f / (1.0f + __expf(-v));
}

// Grid: 8192 blocks. j = bid & 1023, g = bid >> 10 (g in [0,8)).
// Blocks sharing row j are 1024 apart => same XCD under bid%8 round-robin =>
// c_x/c_u/c_U/w row j L2-resident across its 8 g-blocks.
// Each block: row j, batches b in [g*4, g*4+4), 256 threads x 4 consecutive k.
// ALL 12 global vector loads (4X + 4U + 4h) are posted before any compute:
// first vmcnt wait gates only the first batch; the rest stay in flight
// (R1-R3 lesson: achieved BW ~ waves/CU x bytes posted per wave).
__global__ __launch_bounds__(256, 4) void stp_fused(
    const float* __restrict__ x,    // (IN, B)
    const float* __restrict__ h,    // (B, H)
    const float* __restrict__ X,    // (B, H, H)
    const float* __restrict__ U,    // (B, H, H)
    const float* __restrict__ c_x,  // (H, H)
    const float* __restrict__ c_u,  // (H, H)
    const float* __restrict__ c_U,  // (H, H)
    const float* __restrict__ c_h,  // (H, 1)
    const float* __restrict__ w,    // (H, H)
    const float* __restrict__ p,    // (H, IN)
    const float* __restrict__ bias, // (H, 1)
    float* __restrict__ out)        // (B, H)
{
    const int j = blockIdx.x & (HH - 1);
    const int g = blockIdx.x >> 10;
    const int t = threadIdx.x;
    const int lane = t & 63;
    const int wave = t >> 6;
    const int k0 = t * 4;

    __shared__ float px_part[64][BG];   // p@x partials: seg x b_local (1 KB)
    __shared__ float rec_part[BG][4];   // rec partials: b_local x wave

    // ---- post the entire batch of X/U/h loads FIRST ----
    v4f Xb[BG], Ub[BG], hkb[BG];
    float hjb[BG];
    #pragma unroll
    for (int i = 0; i < BG; ++i) {
        const int b = g * BG + i;
        const int rb = (b * HH + j) * HH + k0;
        Xb[i] = __builtin_nontemporal_load((const v4f*)(X + rb));
        Ub[i] = __builtin_nontemporal_load((const v4f*)(U + rb));
        hkb[i] = *(const v4f*)(h + b * HH + k0);
        hjb[i] = h[b * HH + j];
    }

    // ---- fused p@x prologue: 64 segs x 4 batches, 8 inputs per seg ----
    // (runs while the X/U loads are in flight)
    {
        const int b_id = t & 3;
        const int seg = t >> 2;                 // 0..63
        const int b = g * BG + b_id;
        float acc = 0.0f;
        const float* prow = p + j * INW + seg * 8;
        const float* xcol = x + (seg * 8) * BB + b;
        #pragma unroll
        for (int i = 0; i < 8; ++i)
            acc = fmaf(prow[i], xcol[i * BB], acc);
        px_part[seg][b_id] = acc;
    }

    // ---- per-k parameters for row j (L2-hot: 8 blocks/row on one XCD) ----
    v4f cx4 = *(const v4f*)(c_x + j * HH + k0);
    v4f cu4 = *(const v4f*)(c_u + j * HH + k0);
    v4f cC4 = *(const v4f*)(c_U + j * HH + k0);
    v4f wv4 = *(const v4f*)(w + j * HH + k0);

    float zx[4], ozx[4], Acoef[4], ozu[4], Ucap[4], wr[4];
    #pragma unroll
    for (int c = 0; c < 4; ++c) {
        float zxx = Z_MIN_C + Z_RANGE_C * sigmoidf_(cx4[c]);
        float zuu = Z_MIN_C + Z_RANGE_C * sigmoidf_(cu4[c]);
        float ucc = 0.9f * sigmoidf_(cC4[c]);
        zx[c] = zxx;
        ozx[c] = 1.0f - zxx;
        ozu[c] = 1.0f - zuu;
        Ucap[c] = ucc;
        Acoef[c] = ucc * zuu;
        wr[c] = wv4[c];
    }

    // ---- consume the 4 batches ----
    float s[BG];
    #pragma unroll
    for (int i = 0; i < BG; ++i) {
        const float hjv = hjb[i];
        float ss = 0.0f;
        #pragma unroll
        for (int c = 0; c < 4; ++c) {
            // X_new = z_x + (1-z_x)*X - U*(X*hj)
            float Xn = fmaf(ozx[c], Xb[i][c], zx[c]);
            Xn = fmaf(-Ub[i][c], Xb[i][c] * hjv, Xn);
            // U_new = Ucap*z_u + (1-z_u)*U + Ucap*hj*(1-U), clamp [Ucap, 1]
            float Un = fmaf(ozu[c], Ub[i][c], Acoef[c]);
            Un = fmaf(Ucap[c] * hjv, 1.0f - Ub[i][c], Un);
            Un = fminf(fmaxf(Un, Ucap[c]), 1.0f);
            // rec contribution: w*U_new*X_new * h[b,k]
            ss = fmaf(wr[c] * hkb[i][c], Un * Xn, ss);
        }
        s[i] = ss;
    }

    // ---- deferred cross-lane reductions (4 independent shuffle chains) ----
    #pragma unroll
    for (int i = 0; i < BG; ++i) {
        float v = s[i];
        #pragma unroll
        for (int off = 32; off > 0; off >>= 1)
            v += __shfl_xor(v, off);
        if (lane == 0) rec_part[i][wave] = v;
    }
    __syncthreads();

    // ---- finalize: thread t = local batch ----
    if (t < BG) {
        const int b = g * BG + t;
        float rec = rec_part[t][0] + rec_part[t][1] + rec_part[t][2] + rec_part[t][3];
        float px = 0.0f;
        #pragma unroll
        for (int sgi = 0; sgi < 64; ++sgi) px += px_part[sgi][t];
        float pre = rec + px + bias[j];
        float zh = E_H_C * sigmoidf_(c_h[j]);
        float hv = h[b * HH + j];
        out[b * HH + j] = (1.0f - zh) * hv + zh * sigmoidf_(pre);
    }
}

extern "C" void kernel_launch(void* const* d_in, const int* in_sizes, int n_in,
                              void* d_out, int out_size, void* d_ws, size_t ws_size,
                              hipStream_t stream) {
    const float* x   = (const float*)d_in[0];
    const float* h   = (const float*)d_in[1];
    const float* X   = (const float*)d_in[2];
    const float* U   = (const float*)d_in[3];
    const float* c_x = (const float*)d_in[4];
    const float* c_u = (const float*)d_in[5];
    const float* c_U = (const float*)d_in[6];
    const float* c_h = (const float*)d_in[7];
    const float* w   = (const float*)d_in[8];
    const float* p   = (const float*)d_in[9];
    const float* b   = (const float*)d_in[10];
    float* out = (float*)d_out;

    stp_fused<<<HH * 8, 256, 0, stream>>>(x, h, X, U, c_x, c_u, c_U, c_h, w, p, b, out);
}

// Round 5
// 297.884 us; speedup vs baseline: 1.0065x; 1.0065x over previous
//
#include <hip/hip_runtime.h>

#define HH 1024
#define INW 512
#define BB 32
#define BG 4             // batches per block: B=32 split across 8 blocks per row
#define Z_MIN_C 0.001f
#define Z_RANGE_C 0.099f
#define E_H_C 0.5f

typedef float v4f __attribute__((ext_vector_type(4)));

__device__ __forceinline__ float sigmoidf_(float v) {
    return 1.0f / (1.0f + __expf(-v));
}

// ---------------- Kernel A: pre0[b,j] = (p @ x)[j,b] + bias[j] ----------------
// One wave per j-row. lane = (b = lane&31, half = lane>>5); i in half*256..+256.
// x reads: at fixed i, lanes 0-31 hit x[i*32 + 0..31] = 128 B contiguous ->
// 1-2 transactions per wave-inst (x is 64 KB, L2-hot after first touches).
__global__ __launch_bounds__(256) void px_kernel(
    const float* __restrict__ x,    // (IN, B)
    const float* __restrict__ p,    // (H, IN)
    const float* __restrict__ bias, // (H, 1)
    float* __restrict__ pre0)       // (B, H) in workspace
{
    const int wv = threadIdx.x >> 6;
    const int lane = threadIdx.x & 63;
    const int j = blockIdx.x * 4 + wv;
    const int b = lane & 31;
    const int half = lane >> 5;

    const float* pr = p + j * INW + half * 256;
    const float* xc = x + (half * 256) * BB + b;
    float acc = 0.0f;
    #pragma unroll 8
    for (int i = 0; i < 256; ++i)
        acc = fmaf(pr[i], xc[i * BB], acc);
    acc += __shfl_xor(acc, 32);          // combine the two i-halves
    if (lane < 32)
        pre0[lane * HH + j] = acc + bias[j];
}

// ---------------- Kernel B: stream X/U, fuse everything else ----------------
// Grid: 8192 blocks. j = bid & 1023, g = bid >> 10 (g in [0,8)).
// Blocks of one row are 1024 apart -> same XCD (1024%8==0) -> param rows L2-hot.
// Exactly ONE block owns each (b,j) pair, so no cross-block accumulation.
// All 12 X/U/h vector loads are posted before anything else; the L2-hot param
// loads + sigmoid math execute under their flight. launch_bounds(256,4) gives
// the allocator 128 VGPRs so the whole burst stays live (R4 lesson: at 40
// VGPRs the compiler serialized the queue -> 23% HBM).
__global__ __launch_bounds__(256, 4) void stp_fused(
    const float* __restrict__ h,    // (B, H)
    const float* __restrict__ X,    // (B, H, H)
    const float* __restrict__ U,    // (B, H, H)
    const float* __restrict__ c_x,  // (H, H)
    const float* __restrict__ c_u,  // (H, H)
    const float* __restrict__ c_U,  // (H, H)
    const float* __restrict__ c_h,  // (H, 1)
    const float* __restrict__ w,    // (H, H)
    const float* __restrict__ pre0, // (B, H) workspace from px_kernel
    float* __restrict__ out)        // (B, H)
{
    const int j = blockIdx.x & (HH - 1);
    const int g = blockIdx.x >> 10;
    const int t = threadIdx.x;
    const int lane = t & 63;
    const int wave = t >> 6;
    const int k0 = t * 4;

    __shared__ float rec_part[BG][4];   // b_local x wave

    // ---- post the entire X/U/h burst FIRST (12 x dwordx4 + 4 scalar) ----
    v4f Xb[BG], Ub[BG], hkb[BG];
    float hjb[BG];
    #pragma unroll
    for (int i = 0; i < BG; ++i) {
        const int b = g * BG + i;
        const int rb = (b * HH + j) * HH + k0;
        Xb[i] = __builtin_nontemporal_load((const v4f*)(X + rb));
        Ub[i] = __builtin_nontemporal_load((const v4f*)(U + rb));
        hkb[i] = *(const v4f*)(h + b * HH + k0);
        hjb[i] = h[b * HH + j];
    }

    // ---- param loads (L2-hot) + sigmoid math overlap the burst's flight ----
    v4f cx4 = *(const v4f*)(c_x + j * HH + k0);
    v4f cu4 = *(const v4f*)(c_u + j * HH + k0);
    v4f cC4 = *(const v4f*)(c_U + j * HH + k0);
    v4f wv4 = *(const v4f*)(w + j * HH + k0);

    float zx[4], ozx[4], Acoef[4], ozu[4], Ucap[4], wr[4];
    #pragma unroll
    for (int c = 0; c < 4; ++c) {
        float zxx = Z_MIN_C + Z_RANGE_C * sigmoidf_(cx4[c]);
        float zuu = Z_MIN_C + Z_RANGE_C * sigmoidf_(cu4[c]);
        float ucc = 0.9f * sigmoidf_(cC4[c]);
        zx[c] = zxx;
        ozx[c] = 1.0f - zxx;
        ozu[c] = 1.0f - zuu;
        Ucap[c] = ucc;
        Acoef[c] = ucc * zuu;
        wr[c] = wv4[c];
    }

    // ---- consume ----
    float s[BG];
    #pragma unroll
    for (int i = 0; i < BG; ++i) {
        const float hjv = hjb[i];
        float ss = 0.0f;
        #pragma unroll
        for (int c = 0; c < 4; ++c) {
            // X_new = z_x + (1-z_x)*X - U*(X*hj)
            float Xn = fmaf(ozx[c], Xb[i][c], zx[c]);
            Xn = fmaf(-Ub[i][c], Xb[i][c] * hjv, Xn);
            // U_new = Ucap*z_u + (1-z_u)*U + Ucap*hj*(1-U), clamp [Ucap, 1]
            float Un = fmaf(ozu[c], Ub[i][c], Acoef[c]);
            Un = fmaf(Ucap[c] * hjv, 1.0f - Ub[i][c], Un);
            Un = fminf(fmaxf(Un, Ucap[c]), 1.0f);
            // rec contribution: w*U_new*X_new * h[b,k]
            ss = fmaf(wr[c] * hkb[i][c], Un * Xn, ss);
        }
        s[i] = ss;
    }

    // ---- cross-lane reductions (4 independent shuffle chains) ----
    #pragma unroll
    for (int i = 0; i < BG; ++i) {
        float v = s[i];
        #pragma unroll
        for (int off = 32; off > 0; off >>= 1)
            v += __shfl_xor(v, off);
        if (lane == 0) rec_part[i][wave] = v;
    }
    __syncthreads();

    // ---- finalize: thread t = local batch (sole owner of (b,j)) ----
    if (t < BG) {
        const int b = g * BG + t;
        float rec = rec_part[t][0] + rec_part[t][1] + rec_part[t][2] + rec_part[t][3];
        float pre = pre0[b * HH + j] + rec;
        float zh = E_H_C * sigmoidf_(c_h[j]);
        float hv = h[b * HH + j];
        out[b * HH + j] = (1.0f - zh) * hv + zh * sigmoidf_(pre);
    }
}

extern "C" void kernel_launch(void* const* d_in, const int* in_sizes, int n_in,
                              void* d_out, int out_size, void* d_ws, size_t ws_size,
                              hipStream_t stream) {
    const float* x   = (const float*)d_in[0];
    const float* h   = (const float*)d_in[1];
    const float* X   = (const float*)d_in[2];
    const float* U   = (const float*)d_in[3];
    const float* c_x = (const float*)d_in[4];
    const float* c_u = (const float*)d_in[5];
    const float* c_U = (const float*)d_in[6];
    const float* c_h = (const float*)d_in[7];
    const float* w   = (const float*)d_in[8];
    const float* p   = (const float*)d_in[9];
    const float* b   = (const float*)d_in[10];
    float* out = (float*)d_out;
    float* pre0 = (float*)d_ws;          // 32*1024 floats = 128 KB

    px_kernel<<<HH / 4, 256, 0, stream>>>(x, p, b, pre0);
    stp_fused<<<HH * 8, 256, 0, stream>>>(h, X, U, c_x, c_u, c_U, c_h, w, pre0, out);
}